// Round 12
// baseline (1146.474 us; speedup 1.0000x reference)
//
#include <hip/hip_runtime.h>

// LSTM B=256, T=2048, H=128, gates 4H=512, deferred fc projection.
// Round-11 lesson: wall 1210 cyc/step = MFMA floor (512 cyc: 128 MFMA/CU @
// ~16 cyc/SIMD, M=1/16 structural) + TWO serialized ~280-cyc VALU tails
// (2 waves/SIMD, in-order issue, lockstep barrier -> tails contend VALU).
// This round: 4 waves (1/SIMD). Wave w owns units [32w,32w+32) = 8 chains
// (4 gate types x 2 unit-blocks) x 4 K-chunks = 32 MFMA. Same per-SIMD MFMA
// time, but ONE tail exposure and zero VALU contention. Tail trimmed by
// folding bias + x*W_ih into acc elem-0 init (all A rows identical -> D rows
// are replicas; junk in elems 1-3 is never read).
//
// mfma_f32_16x16x32_f16 packing safety: A[q,e] = h[32kc+8q+e] and
// B[q,e] = W_hh[row][32kc+8q+e] share the HW (lane,elem)->k map -> exact for
// any bijection. D: col=lane&15, row=(lane>>4)*4+reg (m89-verified); all A
// rows = h -> every lane's reg 0 holds gate[col].

typedef _Float16 half2v __attribute__((ext_vector_type(2)));
typedef _Float16 f16x8  __attribute__((ext_vector_type(8)));
typedef float    f32x4  __attribute__((ext_vector_type(4)));

constexpr int NB = 256;
constexpr int NT = 2048;
constexpr int NH = 128;

__device__ __forceinline__ float fexp2(float x) {
    float r;
    asm("v_exp_f32 %0, %1" : "=v"(r) : "v"(x));
    return r;
}
__device__ __forceinline__ float frcp(float x) {
    float r;
    asm("v_rcp_f32 %0, %1" : "=v"(r) : "v"(x));
    return r;
}
__device__ __forceinline__ float fsig(float x) {   // 1/(1+2^(-x*log2e))
    return frcp(1.f + fexp2(x * -1.44269504f));
}
__device__ __forceinline__ float ftanh(float x) {  // 2/(1+2^(-2x*log2e)) - 1
    return fmaf(2.f, frcp(1.f + fexp2(x * -2.88539008f)), -1.f);
}

__device__ __forceinline__ unsigned packh2(float lo, float hi) {
    half2v p;
    p.x = (_Float16)lo;
    p.y = (_Float16)hi;
    return __builtin_bit_cast(unsigned, p);
}

__device__ __forceinline__ float dot2(unsigned int w, unsigned int h, float acc) {
    half2v a = __builtin_bit_cast(half2v, w);
    half2v b = __builtin_bit_cast(half2v, h);
#if __has_builtin(__builtin_amdgcn_fdot2)
    return __builtin_amdgcn_fdot2(a, b, acc, false);
#else
    float r;
    asm("v_dot2_f32_f16 %0, %1, %2, %3" : "=v"(r) : "v"(a), "v"(b), "v"(acc));
    return r;
#endif
}

__device__ __forceinline__ f32x4 mfma32(f16x8 a, f16x8 b, f32x4 c) {
#if __has_builtin(__builtin_amdgcn_mfma_f32_16x16x32_f16)
    return __builtin_amdgcn_mfma_f32_16x16x32_f16(a, b, c, 0, 0, 0);
#else
    asm("v_mfma_f32_16x16x32_f16 %0, %1, %2, %0" : "+v"(c) : "v"(a), "v"(b));
    return c;
#endif
}

// barrier with LDS visibility, NO vmcnt drain (fire-and-forget h stores
// stay off the 2048-iteration critical path)
__device__ __forceinline__ void barrier_lds() {
    asm volatile("s_waitcnt lgkmcnt(0)" ::: "memory");
    __builtin_amdgcn_s_barrier();
    asm volatile("" ::: "memory");
}

template <bool DEFER_FC>
__global__ __launch_bounds__(256, 1)
void lstm_k1(const float* __restrict__ x, const float* __restrict__ W_ih,
             const float* __restrict__ W_hh, const float* __restrict__ b_ih,
             const float* __restrict__ b_hh, const float* __restrict__ fc_w,
             const float* __restrict__ fc_b, float* __restrict__ out,
             _Float16* __restrict__ hws) {
    __shared__ __align__(16) float    x_lds[NT];
    __shared__ __align__(16) _Float16 h_lds[2][NH];  // double buffer
    __shared__ float red[4];                         // fallback fc partials

    const int b    = blockIdx.x;
    const int t    = threadIdx.x;   // 0..255
    const int lane = t & 63;
    const int w    = t >> 6;        // wave 0..3: units [32w, 32w+32)
    const int q    = lane >> 4;     // k-subgroup 0..3
    const int nlo  = lane & 15;
    const int u0   = 32 * w + nlo;  // this lane's unit (block 0)
    const int u1   = u0 + 16;       // this lane's unit (block 1)

    // preload x row (256 threads x 2 float4)
    ((float4*)x_lds)[t]       = ((const float4*)(x + (size_t)b * NT))[t];
    ((float4*)x_lds)[t + 256] = ((const float4*)(x + (size_t)b * NT))[t + 256];
    if (t < NH) h_lds[0][t] = (_Float16)0.f;

    // ---- persistent B-frags: 8 chains (g,ub) x 4 K-chunks, f16x8 ----
    // chain r = 2*g + ub; row = g*NH + 32w + 16*ub + nlo
    // lane l, elem e of bw[r][kc] = W_hh[row][32*kc + 8q + e]
    f16x8 bw[8][4];
#pragma unroll
    for (int g = 0; g < 4; ++g) {
#pragma unroll
        for (int ub = 0; ub < 2; ++ub) {
            const float* wrow =
                W_hh + (size_t)(g * NH + 32 * w + 16 * ub + nlo) * NH;
#pragma unroll
            for (int kc = 0; kc < 4; ++kc) {
                float4 f0 = *(const float4*)(wrow + kc * 32 + q * 8);
                float4 f1 = *(const float4*)(wrow + kc * 32 + q * 8 + 4);
                f16x8 v;
                v[0] = (_Float16)f0.x; v[1] = (_Float16)f0.y;
                v[2] = (_Float16)f0.z; v[3] = (_Float16)f0.w;
                v[4] = (_Float16)f1.x; v[5] = (_Float16)f1.y;
                v[6] = (_Float16)f1.z; v[7] = (_Float16)f1.w;
                bw[2 * g + ub][kc] = v;
            }
        }
    }
#pragma unroll
    for (int r = 0; r < 8; ++r)
#pragma unroll
        for (int kc = 0; kc < 4; ++kc) asm volatile("" : "+v"(bw[r][kc]));

    // per-lane gate constants for units u0, u1
    const float bi0 = b_ih[u0] + b_hh[u0];
    const float bf0 = b_ih[NH + u0] + b_hh[NH + u0];
    const float bz0 = b_ih[2 * NH + u0] + b_hh[2 * NH + u0];
    const float bo0 = b_ih[3 * NH + u0] + b_hh[3 * NH + u0];
    const float bi1 = b_ih[u1] + b_hh[u1];
    const float bf1 = b_ih[NH + u1] + b_hh[NH + u1];
    const float bz1 = b_ih[2 * NH + u1] + b_hh[2 * NH + u1];
    const float bo1 = b_ih[3 * NH + u1] + b_hh[3 * NH + u1];
    const float wi0 = W_ih[u0], wf0 = W_ih[NH + u0];
    const float wz0 = W_ih[2 * NH + u0], wo0 = W_ih[3 * NH + u0];
    const float wi1 = W_ih[u1], wf1 = W_ih[NH + u1];
    const float wz1 = W_ih[2 * NH + u1], wo1 = W_ih[3 * NH + u1];

    float c0 = 0.f, h0 = 0.f, c1 = 0.f, h1 = 0.f;  // replicated across q
    float fcw0 = 0.f, fcw1 = 0.f, fcb = 0.f;
    if (!DEFER_FC) {
        fcw0 = fc_w[u0];
        fcw1 = fc_w[u1];
        fcb  = fc_b[0];
    }

    float*    outp = out + (size_t)b * NT;
    _Float16* hrow = DEFER_FC ? (hws + (size_t)b * NT * NH) : (_Float16*)nullptr;

    __syncthreads();

    for (int step = 0; step < NT; ++step) {
        // ---- A-frags: uniform broadcast reads (all 16 A rows = h) ----
        const _Float16* hbuf = h_lds[step & 1];
        f16x8 av[4];
#pragma unroll
        for (int kc = 0; kc < 4; ++kc)
            av[kc] = *(const f16x8*)(hbuf + kc * 32 + q * 8);
        float xv = x_lds[step];

        // ---- acc init: elem0 = bias + x*W_ih (no post-add needed) ----
        f32x4 ai0 = {fmaf(xv, wi0, bi0), 0.f, 0.f, 0.f};
        f32x4 af0 = {fmaf(xv, wf0, bf0), 0.f, 0.f, 0.f};
        f32x4 az0 = {fmaf(xv, wz0, bz0), 0.f, 0.f, 0.f};
        f32x4 ao0 = {fmaf(xv, wo0, bo0), 0.f, 0.f, 0.f};
        f32x4 ai1 = {fmaf(xv, wi1, bi1), 0.f, 0.f, 0.f};
        f32x4 af1 = {fmaf(xv, wf1, bf1), 0.f, 0.f, 0.f};
        f32x4 az1 = {fmaf(xv, wz1, bz1), 0.f, 0.f, 0.f};
        f32x4 ao1 = {fmaf(xv, wo1, bo1), 0.f, 0.f, 0.f};

        // ---- 32 MFMA: 8 interleaved chains x 4 K-chunks ----
#pragma unroll
        for (int kc = 0; kc < 4; ++kc) {
            ai0 = mfma32(av[kc], bw[0][kc], ai0);
            ai1 = mfma32(av[kc], bw[1][kc], ai1);
            af0 = mfma32(av[kc], bw[2][kc], af0);
            af1 = mfma32(av[kc], bw[3][kc], af1);
            az0 = mfma32(av[kc], bw[4][kc], az0);
            az1 = mfma32(av[kc], bw[5][kc], az1);
            ao0 = mfma32(av[kc], bw[6][kc], ao0);
            ao1 = mfma32(av[kc], bw[7][kc], ao1);
        }

        // ---- tail: activations + cell update for both units ----
        float gi0 = fsig(ai0[0]), gf0 = fsig(af0[0]);
        float gz0 = ftanh(az0[0]), go0 = fsig(ao0[0]);
        c0 = fmaf(gf0, c0, gi0 * gz0);
        h0 = go0 * ftanh(c0);
        float gi1 = fsig(ai1[0]), gf1 = fsig(af1[0]);
        float gz1 = ftanh(az1[0]), go1 = fsig(ao1[0]);
        c1 = fmaf(gf1, c1, gi1 * gz1);
        h1 = go1 * ftanh(c1);

        if (lane < 16) {
            _Float16* hnxt = h_lds[(step + 1) & 1];
            hnxt[u0] = (_Float16)h0;
            hnxt[u1] = (_Float16)h1;
            if (DEFER_FC) {
                hrow[(size_t)step * NH + u0] = (_Float16)h0;  // fire-and-forget
                hrow[(size_t)step * NH + u1] = (_Float16)h1;
            }
        }
        if (!DEFER_FC) {
            float p = (lane < 16) ? fmaf(h0, fcw0, h1 * fcw1) : 0.f;
#pragma unroll
            for (int m = 32; m >= 1; m >>= 1) p += __shfl_xor(p, m, 64);
            if (lane == 0) red[w] = p;
            __syncthreads();
            if (t == 0)
                outp[step] = ftanh(red[0] + red[1] + red[2] + red[3] + fcb);
        }
        barrier_lds();  // h_lds[next] visible to all waves
    }

    // ---- final hT, cT ([1,B,H] each, after out) ----
    if (lane < 16) {
        float* hT = out + (size_t)NB * NT;
        float* cT = hT + (size_t)NB * NH;
        hT[b * NH + u0] = h0;
        hT[b * NH + u1] = h1;
        cT[b * NH + u0] = c0;
        cT[b * NH + u1] = c1;
    }
}

// Kernel 2: out[b,t] = tanh(dot(h[b,t,:], fc_w) + fc_b). Memory-bound.
__global__ __launch_bounds__(256) void fc_k2(const _Float16* __restrict__ hws,
                                             const float* __restrict__ fc_w,
                                             const float* __restrict__ fc_b,
                                             float* __restrict__ out) {
    __shared__ unsigned wlds[64];
    const int t = threadIdx.x;
    if (t < 64) {
        float2 f = ((const float2*)fc_w)[t];
        wlds[t] = packh2(f.x, f.y);
    }
    __syncthreads();

    const size_t idx = (size_t)blockIdx.x * 256 + t;
    const uint4* hp = (const uint4*)(hws + idx * NH);
    const uint4* wp = (const uint4*)wlds;
    float acc = 0.f;
#pragma unroll
    for (int j = 0; j < 16; ++j) {
        uint4 hv = hp[j];
        uint4 wv = wp[j];
        acc = dot2(hv.x, wv.x, acc);
        acc = dot2(hv.y, wv.y, acc);
        acc = dot2(hv.z, wv.z, acc);
        acc = dot2(hv.w, wv.w, acc);
    }
    out[idx] = ftanh(acc + fc_b[0]);
}

extern "C" void kernel_launch(void* const* d_in, const int* in_sizes, int n_in,
                              void* d_out, int out_size, void* d_ws, size_t ws_size,
                              hipStream_t stream) {
    const float* x    = (const float*)d_in[0];
    const float* W_ih = (const float*)d_in[1];
    const float* W_hh = (const float*)d_in[2];
    const float* b_ih = (const float*)d_in[3];
    const float* b_hh = (const float*)d_in[4];
    const float* fc_w = (const float*)d_in[5];
    const float* fc_b = (const float*)d_in[6];
    float* out = (float*)d_out;

    const size_t need = (size_t)NB * NT * NH * sizeof(_Float16);  // 128 MB
    if (ws_size >= need) {
        _Float16* hws = (_Float16*)d_ws;
        lstm_k1<true><<<dim3(NB), dim3(256), 0, stream>>>(
            x, W_ih, W_hh, b_ih, b_hh, fc_w, fc_b, out, hws);
        fc_k2<<<dim3(NB * NT / 256), dim3(256), 0, stream>>>(hws, fc_w, fc_b, out);
    } else {
        lstm_k1<false><<<dim3(NB), dim3(256), 0, stream>>>(
            x, W_ih, W_hh, b_ih, b_hh, fc_w, fc_b, out, nullptr);
    }
}

// Round 13
// 902.850 us; speedup vs baseline: 1.2698x; 1.2698x over previous
//
#include <hip/hip_runtime.h>

// LSTM B=256, T=2048, H=128, gates 4H=512, deferred fc projection.
// Round-12 lessons: (a) MFMA floor recalibrated: 16x16x32_f16 is ~19 cyc per
// SIMD (4.85 cyc per CU, m06) -> 32 MFMA/SIMD/step = 545-620 cyc, matching
// MfmaUtil across R10-R12. (b) 1 wave/SIMD removes cross-wave overlap ->
// regression; 2 waves/SIMD (R11) is right but lockstep aligns both waves'
// phases so the ~280-cyc/wave VALU tail is fully exposed after the MFMA phase.
//
// This round (R11 structure + 3 changes):
// 1. Persistent accs, junk elems 1-3 never reset (finite: all D rows equal
//    gate preact, |sum| < 6500 over 2048 steps); per-step init writes only
//    elem 0 = bias + x*W_ih (folds bias/x, kills 20 VALU ops/wave/step).
// 2. Exec-masked tail (lane<16): activations/cell only on q=0 group; CDNA
//    can skip all-zero exec halves of a wave64 -> tail issue cost halves.
// 3. Asymmetric s_setprio: waves 0-3 prio 1, waves 4-7 prio 0 (SIMD s hosts
//    waves s, s+4) -> high-prio wave finishes MFMAs early, its VALU tail
//    overlaps the other wave's MFMA phase (separate pipes, m114).
//
// mfma_f32_16x16x32_f16 packing safety: A[q,e] = h[32kc+8q+e] and
// B[q,e] = W_hh[row][32kc+8q+e] share the HW (lane,elem)->k map -> exact for
// any bijection. D: col=lane&15, row=(lane>>4)*4+reg (m89-verified); all A
// rows = h -> every lane's reg 0 holds gate[col].

typedef _Float16 half2v __attribute__((ext_vector_type(2)));
typedef _Float16 f16x8  __attribute__((ext_vector_type(8)));
typedef float    f32x4  __attribute__((ext_vector_type(4)));

constexpr int NB = 256;
constexpr int NT = 2048;
constexpr int NH = 128;

__device__ __forceinline__ float fexp2(float x) {
    float r;
    asm("v_exp_f32 %0, %1" : "=v"(r) : "v"(x));
    return r;
}
__device__ __forceinline__ float frcp(float x) {
    float r;
    asm("v_rcp_f32 %0, %1" : "=v"(r) : "v"(x));
    return r;
}
__device__ __forceinline__ float fsig(float x) {   // 1/(1+2^(-x*log2e))
    return frcp(1.f + fexp2(x * -1.44269504f));
}
__device__ __forceinline__ float ftanh(float x) {  // 2/(1+2^(-2x*log2e)) - 1
    return fmaf(2.f, frcp(1.f + fexp2(x * -2.88539008f)), -1.f);
}

__device__ __forceinline__ unsigned packh2(float lo, float hi) {
    half2v p;
    p.x = (_Float16)lo;
    p.y = (_Float16)hi;
    return __builtin_bit_cast(unsigned, p);
}

__device__ __forceinline__ float dot2(unsigned int w, unsigned int h, float acc) {
    half2v a = __builtin_bit_cast(half2v, w);
    half2v b = __builtin_bit_cast(half2v, h);
#if __has_builtin(__builtin_amdgcn_fdot2)
    return __builtin_amdgcn_fdot2(a, b, acc, false);
#else
    float r;
    asm("v_dot2_f32_f16 %0, %1, %2, %3" : "=v"(r) : "v"(a), "v"(b), "v"(acc));
    return r;
#endif
}

__device__ __forceinline__ f32x4 mfma32(f16x8 a, f16x8 b, f32x4 c) {
#if __has_builtin(__builtin_amdgcn_mfma_f32_16x16x32_f16)
    return __builtin_amdgcn_mfma_f32_16x16x32_f16(a, b, c, 0, 0, 0);
#else
    asm("v_mfma_f32_16x16x32_f16 %0, %1, %2, %0" : "+v"(c) : "v"(a), "v"(b));
    return c;
#endif
}

// barrier with LDS visibility, NO vmcnt drain (fire-and-forget h stores
// stay off the 2048-iteration critical path)
__device__ __forceinline__ void barrier_lds() {
    asm volatile("s_waitcnt lgkmcnt(0)" ::: "memory");
    __builtin_amdgcn_s_barrier();
    asm volatile("" ::: "memory");
}

template <bool DEFER_FC>
__global__ __launch_bounds__(512, 2)
void lstm_k1(const float* __restrict__ x, const float* __restrict__ W_ih,
             const float* __restrict__ W_hh, const float* __restrict__ b_ih,
             const float* __restrict__ b_hh, const float* __restrict__ fc_w,
             const float* __restrict__ fc_b, float* __restrict__ out,
             _Float16* __restrict__ hws) {
    __shared__ __align__(16) float    x_lds[NT];
    __shared__ __align__(16) _Float16 h_lds[2][NH];  // double buffer
    __shared__ float red[8];                         // fallback fc partials

    const int b    = blockIdx.x;
    const int t    = threadIdx.x;   // 0..511
    const int lane = t & 63;
    const int w    = t >> 6;        // wave 0..7: units [16w, 16w+16)
    const int q    = lane >> 4;     // k-subgroup 0..3
    const int nlo  = lane & 15;     // unit-within-wave
    const int u    = 16 * w + nlo;  // this lane's hidden unit

    // phase-shift: one wave per SIMD runs at elevated priority so its VALU
    // tail overlaps the co-resident wave's MFMA phase
    if (w < 4) __builtin_amdgcn_s_setprio(1);

    // preload x row (512 x float4)
    ((float4*)x_lds)[t] = ((const float4*)(x + (size_t)b * NT))[t];
    if (t < NH) h_lds[0][t] = (_Float16)0.f;

    // ---- persistent B-frags: 4 gate-type tiles x 4 K-chunks, f16x8 ----
    // lane l, elem e of bw[g][kc] = W_hh[g*NH + u][32*kc + 8q + e]
    f16x8 bw[4][4];
#pragma unroll
    for (int g = 0; g < 4; ++g) {
        const float* wrow = W_hh + (size_t)(g * NH + u) * NH;
#pragma unroll
        for (int kc = 0; kc < 4; ++kc) {
            float4 f0 = *(const float4*)(wrow + kc * 32 + q * 8);
            float4 f1 = *(const float4*)(wrow + kc * 32 + q * 8 + 4);
            f16x8 v;
            v[0] = (_Float16)f0.x; v[1] = (_Float16)f0.y;
            v[2] = (_Float16)f0.z; v[3] = (_Float16)f0.w;
            v[4] = (_Float16)f1.x; v[5] = (_Float16)f1.y;
            v[6] = (_Float16)f1.z; v[7] = (_Float16)f1.w;
            bw[g][kc] = v;
        }
    }
#pragma unroll
    for (int g = 0; g < 4; ++g)
#pragma unroll
        for (int kc = 0; kc < 4; ++kc) asm volatile("" : "+v"(bw[g][kc]));

    // per-lane gate constants for unit u
    const float bi = b_ih[u] + b_hh[u];
    const float bf = b_ih[NH + u] + b_hh[NH + u];
    const float bz = b_ih[2 * NH + u] + b_hh[2 * NH + u];
    const float bo = b_ih[3 * NH + u] + b_hh[3 * NH + u];
    const float wi = W_ih[u];
    const float wf = W_ih[NH + u];
    const float wz = W_ih[2 * NH + u];
    const float wo = W_ih[3 * NH + u];

    float c = 0.f, h = 0.f;  // cell state of unit u (live on lanes < 16)
    float fcw = 0.f, fcb = 0.f;
    if (!DEFER_FC) {
        fcw = fc_w[u];
        fcb = fc_b[0];
    }

    float*    outp = out + (size_t)b * NT;
    _Float16* hrow = DEFER_FC ? (hws + (size_t)b * NT * NH) : (_Float16*)nullptr;

    // persistent accumulators: elem 0 rewritten each step; elems 1-3 NEVER
    // reset — they accumulate the (identical-row) preact sum, bounded ~6500
    // over 2048 steps, never read. Saves 20 init ops/wave/step.
    f32x4 ai = {0.f, 0.f, 0.f, 0.f}, af = ai, az = ai, ao = ai;

    __syncthreads();

    for (int step = 0; step < NT; ++step) {
        // ---- A-frags: uniform broadcast reads (all 16 A rows = h) ----
        const _Float16* hbuf = h_lds[step & 1];
        float xv = x_lds[step];
        f16x8 av[4];
#pragma unroll
        for (int kc = 0; kc < 4; ++kc)
            av[kc] = *(const f16x8*)(hbuf + kc * 32 + q * 8);

        // ---- acc elem-0 init: bias + x*W_ih folded, 4 fma only ----
        ai[0] = fmaf(xv, wi, bi);
        af[0] = fmaf(xv, wf, bf);
        az[0] = fmaf(xv, wz, bz);
        ao[0] = fmaf(xv, wo, bo);

        // ---- 16 MFMA: 4 gate-type chains x 4 K-chunks ----
#pragma unroll
        for (int kc = 0; kc < 4; ++kc) {
            ai = mfma32(av[kc], bw[0][kc], ai);
            af = mfma32(av[kc], bw[1][kc], af);
            az = mfma32(av[kc], bw[2][kc], az);
            ao = mfma32(av[kc], bw[3][kc], ao);
        }

        // ---- exec-masked tail: only the q=0 group does the scalar work ----
        if (lane < 16) {
            float gi = fsig(ai[0]);
            float gf = fsig(af[0]);
            float gz = ftanh(az[0]);
            float go = fsig(ao[0]);
            c = fmaf(gf, c, gi * gz);
            h = go * ftanh(c);
            _Float16 hh = (_Float16)h;
            h_lds[(step + 1) & 1][u] = hh;
            if (DEFER_FC) hrow[(size_t)step * NH + u] = hh;  // fire-and-forget
        }
        if (!DEFER_FC) {
            float p = (lane < 16) ? h * fcw : 0.f;
#pragma unroll
            for (int m = 8; m >= 1; m >>= 1) p += __shfl_xor(p, m, 64);
            if (lane == 0) red[w] = p;
            __syncthreads();
            if (t == 0) {
                float s = red[0] + red[1] + red[2] + red[3] + red[4] + red[5] +
                          red[6] + red[7];
                outp[step] = ftanh(s + fcb);
            }
        }
        barrier_lds();  // h_lds[next] visible to all waves
    }

    // ---- final hT, cT ([1,B,H] each, after out) ----
    if (lane < 16) {
        float* hT = out + (size_t)NB * NT;
        float* cT = hT + (size_t)NB * NH;
        hT[b * NH + u] = h;
        cT[b * NH + u] = c;
    }
}

// Kernel 2: out[b,t] = tanh(dot(h[b,t,:], fc_w) + fc_b). Memory-bound.
__global__ __launch_bounds__(256) void fc_k2(const _Float16* __restrict__ hws,
                                             const float* __restrict__ fc_w,
                                             const float* __restrict__ fc_b,
                                             float* __restrict__ out) {
    __shared__ unsigned wlds[64];
    const int t = threadIdx.x;
    if (t < 64) {
        float2 f = ((const float2*)fc_w)[t];
        wlds[t] = packh2(f.x, f.y);
    }
    __syncthreads();

    const size_t idx = (size_t)blockIdx.x * 256 + t;
    const uint4* hp = (const uint4*)(hws + idx * NH);
    const uint4* wp = (const uint4*)wlds;
    float acc = 0.f;
#pragma unroll
    for (int j = 0; j < 16; ++j) {
        uint4 hv = hp[j];
        uint4 wv = wp[j];
        acc = dot2(hv.x, wv.x, acc);
        acc = dot2(hv.y, wv.y, acc);
        acc = dot2(hv.z, wv.z, acc);
        acc = dot2(hv.w, wv.w, acc);
    }
    out[idx] = ftanh(acc + fc_b[0]);
}

extern "C" void kernel_launch(void* const* d_in, const int* in_sizes, int n_in,
                              void* d_out, int out_size, void* d_ws, size_t ws_size,
                              hipStream_t stream) {
    const float* x    = (const float*)d_in[0];
    const float* W_ih = (const float*)d_in[1];
    const float* W_hh = (const float*)d_in[2];
    const float* b_ih = (const float*)d_in[3];
    const float* b_hh = (const float*)d_in[4];
    const float* fc_w = (const float*)d_in[5];
    const float* fc_b = (const float*)d_in[6];
    float* out = (float*)d_out;

    const size_t need = (size_t)NB * NT * NH * sizeof(_Float16);  // 128 MB
    if (ws_size >= need) {
        _Float16* hws = (_Float16*)d_ws;
        lstm_k1<true><<<dim3(NB), dim3(512), 0, stream>>>(
            x, W_ih, W_hh, b_ih, b_hh, fc_w, fc_b, out, hws);
        fc_k2<<<dim3(NB * NT / 256), dim3(256), 0, stream>>>(hws, fc_w, fc_b, out);
    } else {
        lstm_k1<false><<<dim3(NB), dim3(512), 0, stream>>>(
            x, W_ih, W_hh, b_ih, b_hh, fc_w, fc_b, out, nullptr);
    }
}